// Round 5
// baseline (1941.782 us; speedup 1.0000x reference)
//
#include <hip/hip_runtime.h>
#include <hip/hip_bf16.h>

#define D 128
#define NNODES 16384
#define NEDGES 262144
#define NBATCH 2

typedef __attribute__((ext_vector_type(8))) short bf16x8;
typedef __attribute__((ext_vector_type(4))) float f32x4;
typedef __attribute__((ext_vector_type(16))) float f32x16;
typedef __attribute__((ext_vector_type(4))) unsigned int u32x4;
typedef __attribute__((ext_vector_type(2))) unsigned int u32x2;

__device__ __forceinline__ unsigned short f2bf(float f) {
    unsigned int u = __float_as_uint(f);
    unsigned int r = (u + 0x7fffu + ((u >> 16) & 1u)) >> 16;
    return (unsigned short)r;
}

__device__ __forceinline__ unsigned int pk2bf(float lo, float hi) {
    return (unsigned int)f2bf(lo) | ((unsigned int)f2bf(hi) << 16);
}

// --------------------------------------------------------------- weight prep
// w1f: edge layer-1 weights in MFMA-fragment order:
//   frag(ks<24, mb<4): lane l, elem e: value = We1[k][row], k = ks*16+(l>>5)*8+e,
//   row = mb*32+(l&31); stored at ((ks*4+mb)*64 + l)*8 + e  -> 1KB contiguous frags.
// w2f: same for We2 (ks<8).
// wn1t/wn2t: transposed [n][k] bf16 for the node kernel.
__global__ __launch_bounds__(256)
void prep_weights(const float* __restrict__ We1, const float* __restrict__ We2,
                  const float* __restrict__ Wn1, const float* __restrict__ Wn2,
                  unsigned short* __restrict__ w)
{
    int id = blockIdx.x * 256 + threadIdx.x;   // 163840 total
    if (id < 98304) {
        int e = id & 7, lane = (id >> 3) & 63, mb = (id >> 9) & 3, ks = id >> 11;
        int k = ks * 16 + (lane >> 5) * 8 + e;
        int row = mb * 32 + (lane & 31);
        w[id] = f2bf(We1[k * 128 + row]);
    } else if (id < 114688) {
        int i2 = id - 98304;
        int e = i2 & 7, lane = (i2 >> 3) & 63, mb = (i2 >> 9) & 3, ks = i2 >> 11;
        int k = ks * 16 + (lane >> 5) * 8 + e;
        int row = mb * 32 + (lane & 31);
        w[id] = f2bf(We2[k * 128 + row]);
    } else if (id < 147456) {
        int i3 = id - 114688;
        int n = i3 >> 8, k = i3 & 255;
        w[id] = f2bf(Wn1[k * 128 + n]);
    } else {
        int i4 = id - 147456;
        int n = i4 >> 7, k = i4 & 127;
        w[id] = f2bf(Wn2[k * 128 + n]);
    }
}

// ---------------------------------------------------------------- edge kernel
// 128 edges/block, 4 waves, 32 edges/wave. MFMA 32x32x16, A=weights, B=edges.
// H stays in registers; layer1->layer2 via permlane32_swap. No LDS tile.
// launch_bounds(256,2): 256-VGPR budget -> no scratch spill (round-4 lesson:
// (256,4) = 128-reg cap forced ~800MB of spill traffic, 3x regression).
__global__ __launch_bounds__(256, 2)
void edge_kernel(const float* __restrict__ V, const float* __restrict__ E,
                 const int* __restrict__ edges,
                 const unsigned short* __restrict__ w1f, const float* __restrict__ be1,
                 const unsigned short* __restrict__ w2f, const float* __restrict__ be2,
                 float* __restrict__ m0sum, float* __restrict__ m1sum,
                 float* __restrict__ c0, float* __restrict__ c1)
{
    __shared__ int eidx[128][2];

    const int t    = threadIdx.x;
    const int lane = t & 63;
    const int wave = t >> 6;
    const int l31  = lane & 31;
    const int l1   = lane >> 5;

    const long long eflat0 = (long long)blockIdx.x * 128;
    const int b = (int)(eflat0 / NEDGES);

    eidx[t >> 1][t & 1] = edges[(eflat0 + (t >> 1)) * 2 + (t & 1)];
    __syncthreads();

    const int erow = wave * 32 + l31;            // my lane's edge (N-column)
    const int snd = eidx[erow][0], rcv = eidx[erow][1];
    const float* psnd = V + ((long long)b * NNODES + snd) * D;
    const float* prcv = V + ((long long)b * NNODES + rcv) * D;
    const float* pe   = E + (eflat0 + erow) * D;
    const int koff = l1 * 8;

    // ---- layer 1: h^T = We1^T(384x128 -> M=128) x X^T(K=384, N=32 edges) ----
    f32x16 acc[4] = {};
    #pragma unroll
    for (int ks = 0; ks < 24; ++ks) {
        const float* px = (ks < 8) ? psnd : (ks < 16) ? prcv : pe;
        const int pk = (ks & 7) * 16 + koff;
        f32x4 xa = *(const f32x4*)(px + pk);
        f32x4 xb = *(const f32x4*)(px + pk + 4);
        u32x4 xi;
        xi.x = pk2bf(xa[0], xa[1]);
        xi.y = pk2bf(xa[2], xa[3]);
        xi.z = pk2bf(xb[0], xb[1]);
        xi.w = pk2bf(xb[2], xb[3]);
        bf16x8 xf = __builtin_bit_cast(bf16x8, xi);
        #pragma unroll
        for (int mb = 0; mb < 4; ++mb) {
            bf16x8 wf = *(const bf16x8*)(w1f + (((ks * 4 + mb) * 64 + lane) << 3));
            acc[mb] = __builtin_amdgcn_mfma_f32_32x32x16_bf16(wf, xf, acc[mb], 0, 0, 0);
        }
    }

    // bias + silu -> packed bf16 dwords. hdw[mb][q][p] holds hiddens
    // {mb*32 + 8q + 4*l1 + 2p, +1} for edge l31.
    unsigned int hdw[4][4][2];
    #pragma unroll
    for (int mb = 0; mb < 4; ++mb) {
        #pragma unroll
        for (int q = 0; q < 4; ++q) {
            f32x4 bia = *(const f32x4*)(be1 + mb * 32 + q * 8 + l1 * 4);
            float hv[4];
            #pragma unroll
            for (int i = 0; i < 4; ++i) {
                float a = acc[mb][q * 4 + i] + bia[i];
                hv[i] = a / (1.f + __expf(-a));
            }
            hdw[mb][q][0] = pk2bf(hv[0], hv[1]);
            hdw[mb][q][1] = pk2bf(hv[2], hv[3]);
        }
    }

    // ---- layer 2: out^T = We2^T(M=128) x H^T(K=128, N=32 edges) ----
    f32x16 acc2[4] = {};
    #pragma unroll
    for (int ks = 0; ks < 8; ++ks) {
        const int mbq = ks >> 1, k1 = ks & 1;
        u32x2 s0 = __builtin_amdgcn_permlane32_swap(
            hdw[mbq][2 * k1][0], hdw[mbq][2 * k1 + 1][0], false, false);
        u32x2 s1 = __builtin_amdgcn_permlane32_swap(
            hdw[mbq][2 * k1][1], hdw[mbq][2 * k1 + 1][1], false, false);
        u32x4 hi4;
        hi4.x = s0.x; hi4.y = s1.x; hi4.z = s0.y; hi4.w = s1.y;
        bf16x8 hb = __builtin_bit_cast(bf16x8, hi4);
        #pragma unroll
        for (int mb = 0; mb < 4; ++mb) {
            bf16x8 wf = *(const bf16x8*)(w2f + (((ks * 4 + mb) * 64 + lane) << 3));
            acc2[mb] = __builtin_amdgcn_mfma_f32_32x32x16_bf16(wf, hb, acc2[mb], 0, 0, 0);
        }
    }

    // ---- scatter: out cols 0-63 -> m0sum[snd], 64-127 -> m1sum[rcv] ----
    const long long nb0 = (long long)b * NNODES;
    #pragma unroll
    for (int mb = 0; mb < 4; ++mb) {
        float* base = (mb < 2) ? (m0sum + (nb0 + snd) * 64 + mb * 32)
                               : (m1sum + (nb0 + rcv) * 64 + (mb - 2) * 32);
        #pragma unroll
        for (int q = 0; q < 4; ++q) {
            f32x4 bia = *(const f32x4*)(be2 + mb * 32 + q * 8 + l1 * 4);
            #pragma unroll
            for (int i = 0; i < 4; ++i) {
                atomicAdd(base + q * 8 + l1 * 4 + i, acc2[mb][q * 4 + i] + bia[i]);
            }
        }
    }
    if (t < 128) atomicAdd(&c0[nb0 + eidx[t][0]], 1.f);
    else         atomicAdd(&c1[nb0 + eidx[t - 128][1]], 1.f);
}

// ---------------------------------------------------------------- node kernel
#define TE 64
__global__ __launch_bounds__(256)
void node_kernel(const float* __restrict__ V,
                 const float* __restrict__ m0sum, const float* __restrict__ m1sum,
                 const float* __restrict__ c0, const float* __restrict__ c1,
                 const unsigned short* __restrict__ wn1t, const float* __restrict__ bn1,
                 const unsigned short* __restrict__ wn2t, const float* __restrict__ bn2,
                 float* __restrict__ node_emb)
{
    __shared__ unsigned short smem[TE * 264];   // A [64][264]; reused as H [64][136]

    const int t    = threadIdx.x;
    const int lane = t & 63;
    const int wave = t >> 6;
    const int wr   = wave >> 1;
    const int wc   = wave & 1;
    const int l15  = lane & 15;
    const int l4   = lane >> 4;

    const long long nflat0 = (long long)blockIdx.x * TE;

    for (int i = t; i < TE * 64; i += 256) {
        int c4 = i & 63;
        int n  = i >> 6;
        long long node = nflat0 + n;
        float4 v; int off;
        if (c4 < 32) {
            v = *(const float4*)(V + node * 128 + c4 * 4);
            off = c4 * 4;
        } else if (c4 < 48) {
            v = *(const float4*)(m0sum + node * 64 + (c4 - 32) * 4);
            float inv = 1.f / fmaxf(c0[node], 1.f);
            v.x *= inv; v.y *= inv; v.z *= inv; v.w *= inv;
            off = 128 + (c4 - 32) * 4;
        } else {
            v = *(const float4*)(m1sum + node * 64 + (c4 - 48) * 4);
            float inv = 1.f / fmaxf(c1[node], 1.f);
            v.x *= inv; v.y *= inv; v.z *= inv; v.w *= inv;
            off = 192 + (c4 - 48) * 4;
        }
        unsigned int lo = pk2bf(v.x, v.y);
        unsigned int hi = pk2bf(v.z, v.w);
        uint2 p; p.x = lo; p.y = hi;
        *(uint2*)(&smem[n * 264 + c4 * 4]) = p;
    }
    __syncthreads();

    f32x4 acc[2][4] = {};
    {
        const unsigned short* arow = &smem[(wr * 32 + l15) * 264 + l4 * 8];
        const unsigned short* bb0  = wn1t + (wc * 64 + l15) * 256 + l4 * 8;
        for (int ks = 0; ks < 8; ++ks) {
            bf16x8 a0 = *(const bf16x8*)(arow + ks * 32);
            bf16x8 a1 = *(const bf16x8*)(arow + 16 * 264 + ks * 32);
            #pragma unroll
            for (int n = 0; n < 4; ++n) {
                bf16x8 bb = *(const bf16x8*)(bb0 + n * 16 * 256 + ks * 32);
                acc[0][n] = __builtin_amdgcn_mfma_f32_16x16x32_bf16(a0, bb, acc[0][n], 0, 0, 0);
                acc[1][n] = __builtin_amdgcn_mfma_f32_16x16x32_bf16(a1, bb, acc[1][n], 0, 0, 0);
            }
        }
    }
    __syncthreads();

    #pragma unroll
    for (int n = 0; n < 4; ++n) {
        int col = wc * 64 + n * 16 + l15;
        float bias = bn1[col];
        #pragma unroll
        for (int m = 0; m < 2; ++m) {
            #pragma unroll
            for (int i = 0; i < 4; ++i) {
                int row = wr * 32 + m * 16 + l4 * 4 + i;
                float a = acc[m][n][i] + bias;
                smem[row * 136 + col] = f2bf(a / (1.f + __expf(-a)));
            }
        }
    }
    __syncthreads();

    f32x4 acc2[2][4] = {};
    {
        const unsigned short* hrow = &smem[(wr * 32 + l15) * 136 + l4 * 8];
        const unsigned short* bb0  = wn2t + (wc * 64 + l15) * 128 + l4 * 8;
        #pragma unroll
        for (int ks = 0; ks < 4; ++ks) {
            bf16x8 a0 = *(const bf16x8*)(hrow + ks * 32);
            bf16x8 a1 = *(const bf16x8*)(hrow + 16 * 136 + ks * 32);
            #pragma unroll
            for (int n = 0; n < 4; ++n) {
                bf16x8 bb = *(const bf16x8*)(bb0 + n * 16 * 128 + ks * 32);
                acc2[0][n] = __builtin_amdgcn_mfma_f32_16x16x32_bf16(a0, bb, acc2[0][n], 0, 0, 0);
                acc2[1][n] = __builtin_amdgcn_mfma_f32_16x16x32_bf16(a1, bb, acc2[1][n], 0, 0, 0);
            }
        }
    }

    #pragma unroll
    for (int n = 0; n < 4; ++n) {
        int col = wc * 64 + n * 16 + l15;
        float bias = bn2[col];
        #pragma unroll
        for (int m = 0; m < 2; ++m) {
            #pragma unroll
            for (int i = 0; i < 4; ++i) {
                long long row = nflat0 + wr * 32 + m * 16 + l4 * 4 + i;
                node_emb[row * 128 + col] = acc2[m][n][i] + bias;
            }
        }
    }
}

// ------------------------------------------------------------ attention kernel
__global__ __launch_bounds__(256)
void attn_kernel(const float* __restrict__ blocks, const float* __restrict__ node_emb,
                 const float* __restrict__ w_attn, const float* __restrict__ rms_w,
                 float* __restrict__ out)
{
    const int t    = threadIdx.x;
    const int wave = t >> 6;
    const int lane = t & 63;
    const long long node = (long long)blockIdx.x * 4 + wave;
    const int d0 = lane * 2;

    float2 wa = *(const float2*)(w_attn + d0);
    float2 rw = *(const float2*)(rms_w + d0);

    float xs[5][2];
    float lg[5];
    #pragma unroll
    for (int s = 0; s < 5; ++s) {
        const float* src = (s < 4)
            ? (blocks + ((long long)s * NBATCH * NNODES + node) * 128)
            : (node_emb + node * 128);
        float2 x = *(const float2*)(src + d0);
        xs[s][0] = x.x; xs[s][1] = x.y;
        float ss = x.x * x.x + x.y * x.y;
        float wv = wa.x * rw.x * x.x + wa.y * rw.y * x.y;
        #pragma unroll
        for (int m = 1; m < 64; m <<= 1) {
            ss += __shfl_xor(ss, m);
            wv += __shfl_xor(wv, m);
        }
        lg[s] = wv * rsqrtf(ss * (1.f / 128.f) + 1e-6f);
    }

    float mx = lg[0];
    #pragma unroll
    for (int s = 1; s < 5; ++s) mx = fmaxf(mx, lg[s]);
    float ex[5], sum = 0.f;
    #pragma unroll
    for (int s = 0; s < 5; ++s) { ex[s] = __expf(lg[s] - mx); sum += ex[s]; }
    float inv = 1.f / sum;

    float h0 = 0.f, h1 = 0.f;
    #pragma unroll
    for (int s = 0; s < 5; ++s) {
        float a = ex[s] * inv;
        h0 = fmaf(a, xs[s][0], h0);
        h1 = fmaf(a, xs[s][1], h1);
    }
    *(float2*)(out + node * 128 + d0) = make_float2(h0, h1);
}

// ------------------------------------------------------------------- launcher
extern "C" void kernel_launch(void* const* d_in, const int* in_sizes, int n_in,
                              void* d_out, int out_size, void* d_ws, size_t ws_size,
                              hipStream_t stream)
{
    const float* V      = (const float*)d_in[0];
    const float* E      = (const float*)d_in[1];
    const float* blocks = (const float*)d_in[2];
    const float* We1    = (const float*)d_in[3];
    const float* be1    = (const float*)d_in[4];
    const float* We2    = (const float*)d_in[5];
    const float* be2    = (const float*)d_in[6];
    const float* Wn1    = (const float*)d_in[7];
    const float* bn1    = (const float*)d_in[8];
    const float* Wn2    = (const float*)d_in[9];
    const float* bn2    = (const float*)d_in[10];
    const float* w_attn = (const float*)d_in[11];
    const float* rms_w  = (const float*)d_in[12];
    const int*   edges  = (const int*)d_in[13];
    float* out = (float*)d_out;

    float* ws = (float*)d_ws;
    float* m0sum    = ws;                         // BS*N*64
    float* m1sum    = m0sum + 2097152;
    float* c0       = m1sum + 2097152;
    float* c1       = c0 + 32768;
    float* node_emb = c1 + 32768;                 // BS*N*128
    unsigned short* wbf = (unsigned short*)(node_emb + 4194304);  // 163840 bf16
    unsigned short* w1f  = wbf;            // 98304
    unsigned short* w2f  = wbf + 98304;    // 16384
    unsigned short* wn1t = wbf + 114688;   // 32768
    unsigned short* wn2t = wbf + 147456;   // 16384

    (void)hipMemsetAsync(d_ws, 0, (size_t)(2097152 * 2 + 32768 * 2) * sizeof(float), stream);

    prep_weights<<<640, 256, 0, stream>>>(We1, We2, Wn1, Wn2, wbf);

    edge_kernel<<<(NBATCH * NEDGES) / 128, 256, 0, stream>>>(
        V, E, edges, w1f, be1, w2f, be2, m0sum, m1sum, c0, c1);

    node_kernel<<<(NBATCH * NNODES) / TE, 256, 0, stream>>>(
        V, m0sum, m1sum, c0, c1, wn1t, bn1, wn2t, bn2, node_emb);

    attn_kernel<<<(NBATCH * NNODES) / 4, 256, 0, stream>>>(
        blocks, node_emb, w_attn, rms_w, out);
}

// Round 6
// 557.407 us; speedup vs baseline: 3.4836x; 3.4836x over previous
//
#include <hip/hip_runtime.h>
#include <hip/hip_bf16.h>

#define D 128
#define NNODES 16384
#define NEDGES 262144
#define NBATCH 2
#define TE 64

typedef __attribute__((ext_vector_type(8))) short bf16x8;
typedef __attribute__((ext_vector_type(4))) float f32x4;

__device__ __forceinline__ unsigned short f2bf(float f) {
    unsigned int u = __float_as_uint(f);
    unsigned int r = (u + 0x7fffu + ((u >> 16) & 1u)) >> 16;
    return (unsigned short)r;
}

__device__ __forceinline__ unsigned int pk2bf(float lo, float hi) {
    return (unsigned int)f2bf(lo) | ((unsigned int)f2bf(hi) << 16);
}

// --------------------------------------------------------------- weight prep
// Edge-MLP weights in MFMA 16x16x32 B-fragment order: one 1KB contiguous
// chunk per (ks, nblk) fragment -> a wave's frag load is a single fully
// coalesced 1KB transaction (fixes round-2's strided weight reads).
//   w1f[((ks*8 + nblk)*64 + lane)*8 + e] = We1[k][col],
//     k = ks*32 + ((lane>>4)&3)*8 + e, col = nblk*16 + (lane&15), ks<12
//   w2f same with ks<4.
// wn1t/wn2t: plain transposed [n][k] bf16 (node kernel unchanged).
__global__ __launch_bounds__(256)
void prep_weights(const float* __restrict__ We1, const float* __restrict__ We2,
                  const float* __restrict__ Wn1, const float* __restrict__ Wn2,
                  unsigned short* __restrict__ w)
{
    int id = blockIdx.x * 256 + threadIdx.x;   // 114688 total
    if (id < 49152) {
        int e = id & 7, l = (id >> 3) & 63, nblk = (id >> 9) & 7, ks = id >> 12;
        int k = ks * 32 + ((l >> 4) & 3) * 8 + e;
        int col = nblk * 16 + (l & 15);
        w[id] = f2bf(We1[k * 128 + col]);
    } else if (id < 65536) {
        int i2 = id - 49152;
        int e = i2 & 7, l = (i2 >> 3) & 63, nblk = (i2 >> 9) & 7, ks = i2 >> 12;
        int k = ks * 32 + ((l >> 4) & 3) * 8 + e;
        int col = nblk * 16 + (l & 15);
        w[id] = f2bf(We2[k * 128 + col]);
    } else if (id < 98304) {
        int i3 = id - 65536;
        int n = i3 >> 8, k = i3 & 255;
        w[id] = f2bf(Wn1[k * 128 + n]);
    } else {
        int i4 = id - 98304;
        int n = i4 >> 7, k = i4 & 127;
        w[id] = f2bf(Wn2[k * 128 + n]);
    }
}

// ---------------------------------------------------------------- edge kernel
// Round-2 structure (coalesced LDS staging of X, LDS H-tile, coalesced
// scatter) + fragment-ordered contiguous weight loads.
// 64 edges/block, 4 waves in 2x2 grid of 32-edge x 64-col tiles.
__global__ __launch_bounds__(256)
void edge_kernel(const float* __restrict__ V, const float* __restrict__ E,
                 const int* __restrict__ edges,
                 const unsigned short* __restrict__ w1f, const float* __restrict__ be1,
                 const unsigned short* __restrict__ w2f, const float* __restrict__ be2,
                 float* __restrict__ m0sum, float* __restrict__ m1sum,
                 float* __restrict__ c0, float* __restrict__ c1)
{
    __shared__ unsigned short smem[TE * 392];   // X [64][392]; reused as H [64][136]
    __shared__ int eidx[TE][2];

    const int t    = threadIdx.x;
    const int lane = t & 63;
    const int wave = t >> 6;
    const int wr   = wave >> 1;          // edge-row block (32 edges)
    const int wc   = wave & 1;           // out-col block (64 feats); wc=0->m0, 1->m1
    const int l15  = lane & 15;
    const int l4   = lane >> 4;

    const long long eflat0 = (long long)blockIdx.x * TE;
    const int b  = (int)(eflat0 / NEDGES);

    if (t < TE * 2) {
        eidx[t >> 1][t & 1] = edges[(eflat0 + (t >> 1)) * 2 + (t & 1)];
    }
    __syncthreads();

    // stage [snd|rcv|E] rows -> bf16 LDS tile [64][392] (coalesced 512B rows)
    for (int i = t; i < TE * 96; i += 256) {
        int c4 = i % 96;
        int e  = i / 96;
        int part = c4 >> 5;
        int w32  = c4 & 31;
        const float* src;
        if (part == 0)      src = V + ((long long)b * NNODES + eidx[e][0]) * D;
        else if (part == 1) src = V + ((long long)b * NNODES + eidx[e][1]) * D;
        else                src = E + (eflat0 + e) * D;
        float4 v = *(const float4*)(src + w32 * 4);
        uint2 p;
        p.x = pk2bf(v.x, v.y);
        p.y = pk2bf(v.z, v.w);
        *(uint2*)(&smem[e * 392 + c4 * 4]) = p;
    }
    __syncthreads();

    // ---- layer 1: [64x384] @ [384x128] ----
    f32x4 acc[2][4] = {};
    {
        const unsigned short* arow = &smem[(wr * 32 + l15) * 392 + l4 * 8];
        for (int ks = 0; ks < 12; ++ks) {
            bf16x8 a0 = *(const bf16x8*)(arow + ks * 32);
            bf16x8 a1 = *(const bf16x8*)(arow + 16 * 392 + ks * 32);
            #pragma unroll
            for (int n = 0; n < 4; ++n) {
                bf16x8 bb = *(const bf16x8*)(w1f + (((ks * 8 + wc * 4 + n) * 64 + lane) << 3));
                acc[0][n] = __builtin_amdgcn_mfma_f32_16x16x32_bf16(a0, bb, acc[0][n], 0, 0, 0);
                acc[1][n] = __builtin_amdgcn_mfma_f32_16x16x32_bf16(a1, bb, acc[1][n], 0, 0, 0);
            }
        }
    }
    __syncthreads();   // all waves done reading X before H overwrites smem

    // bias + silu -> H tile [64][136] bf16
    #pragma unroll
    for (int n = 0; n < 4; ++n) {
        int col = wc * 64 + n * 16 + l15;
        float bias = be1[col];
        #pragma unroll
        for (int m = 0; m < 2; ++m) {
            #pragma unroll
            for (int i = 0; i < 4; ++i) {
                int row = wr * 32 + m * 16 + l4 * 4 + i;
                float a = acc[m][n][i] + bias;
                smem[row * 136 + col] = f2bf(a / (1.f + __expf(-a)));
            }
        }
    }
    __syncthreads();

    // ---- layer 2: [64x128] @ [128x128] ----
    f32x4 acc2[2][4] = {};
    {
        const unsigned short* hrow = &smem[(wr * 32 + l15) * 136 + l4 * 8];
        #pragma unroll
        for (int ks = 0; ks < 4; ++ks) {
            bf16x8 a0 = *(const bf16x8*)(hrow + ks * 32);
            bf16x8 a1 = *(const bf16x8*)(hrow + 16 * 136 + ks * 32);
            #pragma unroll
            for (int n = 0; n < 4; ++n) {
                bf16x8 bb = *(const bf16x8*)(w2f + (((ks * 8 + wc * 4 + n) * 64 + lane) << 3));
                acc2[0][n] = __builtin_amdgcn_mfma_f32_16x16x32_bf16(a0, bb, acc2[0][n], 0, 0, 0);
                acc2[1][n] = __builtin_amdgcn_mfma_f32_16x16x32_bf16(a1, bb, acc2[1][n], 0, 0, 0);
            }
        }
    }

    // scatter: 16 consecutive lanes cover 16 consecutive feats of ONE node
    // -> 64B-coalesced atomic groups (round-2 pattern, ~294MB WRITE).
    float* dst_arr = wc ? m1sum : m0sum;
    const long long nb0 = (long long)b * NNODES;
    #pragma unroll
    for (int n = 0; n < 4; ++n) {
        int colh = n * 16 + l15;
        float bias = be2[wc * 64 + colh];
        #pragma unroll
        for (int m = 0; m < 2; ++m) {
            #pragma unroll
            for (int i = 0; i < 4; ++i) {
                int erow = wr * 32 + m * 16 + l4 * 4 + i;
                int node = eidx[erow][wc];
                atomicAdd(dst_arr + (nb0 + node) * 64 + colh,
                          acc2[m][n][i] + bias);
            }
        }
    }
    if (t < TE)          atomicAdd(&c0[nb0 + eidx[t][0]], 1.f);
    else if (t < 2 * TE) atomicAdd(&c1[nb0 + eidx[t - TE][1]], 1.f);
}

// ---------------------------------------------------------------- node kernel
__global__ __launch_bounds__(256)
void node_kernel(const float* __restrict__ V,
                 const float* __restrict__ m0sum, const float* __restrict__ m1sum,
                 const float* __restrict__ c0, const float* __restrict__ c1,
                 const unsigned short* __restrict__ wn1t, const float* __restrict__ bn1,
                 const unsigned short* __restrict__ wn2t, const float* __restrict__ bn2,
                 float* __restrict__ node_emb)
{
    __shared__ unsigned short smem[TE * 264];   // A [64][264]; reused as H [64][136]

    const int t    = threadIdx.x;
    const int lane = t & 63;
    const int wave = t >> 6;
    const int wr   = wave >> 1;
    const int wc   = wave & 1;
    const int l15  = lane & 15;
    const int l4   = lane >> 4;

    const long long nflat0 = (long long)blockIdx.x * TE;

    for (int i = t; i < TE * 64; i += 256) {
        int c4 = i & 63;
        int n  = i >> 6;
        long long node = nflat0 + n;
        float4 v; int off;
        if (c4 < 32) {
            v = *(const float4*)(V + node * 128 + c4 * 4);
            off = c4 * 4;
        } else if (c4 < 48) {
            v = *(const float4*)(m0sum + node * 64 + (c4 - 32) * 4);
            float inv = 1.f / fmaxf(c0[node], 1.f);
            v.x *= inv; v.y *= inv; v.z *= inv; v.w *= inv;
            off = 128 + (c4 - 32) * 4;
        } else {
            v = *(const float4*)(m1sum + node * 64 + (c4 - 48) * 4);
            float inv = 1.f / fmaxf(c1[node], 1.f);
            v.x *= inv; v.y *= inv; v.z *= inv; v.w *= inv;
            off = 192 + (c4 - 48) * 4;
        }
        uint2 p;
        p.x = pk2bf(v.x, v.y);
        p.y = pk2bf(v.z, v.w);
        *(uint2*)(&smem[n * 264 + c4 * 4]) = p;
    }
    __syncthreads();

    f32x4 acc[2][4] = {};
    {
        const unsigned short* arow = &smem[(wr * 32 + l15) * 264 + l4 * 8];
        const unsigned short* bb0  = wn1t + (wc * 64 + l15) * 256 + l4 * 8;
        for (int ks = 0; ks < 8; ++ks) {
            bf16x8 a0 = *(const bf16x8*)(arow + ks * 32);
            bf16x8 a1 = *(const bf16x8*)(arow + 16 * 264 + ks * 32);
            #pragma unroll
            for (int n = 0; n < 4; ++n) {
                bf16x8 bb = *(const bf16x8*)(bb0 + n * 16 * 256 + ks * 32);
                acc[0][n] = __builtin_amdgcn_mfma_f32_16x16x32_bf16(a0, bb, acc[0][n], 0, 0, 0);
                acc[1][n] = __builtin_amdgcn_mfma_f32_16x16x32_bf16(a1, bb, acc[1][n], 0, 0, 0);
            }
        }
    }
    __syncthreads();

    #pragma unroll
    for (int n = 0; n < 4; ++n) {
        int col = wc * 64 + n * 16 + l15;
        float bias = bn1[col];
        #pragma unroll
        for (int m = 0; m < 2; ++m) {
            #pragma unroll
            for (int i = 0; i < 4; ++i) {
                int row = wr * 32 + m * 16 + l4 * 4 + i;
                float a = acc[m][n][i] + bias;
                smem[row * 136 + col] = f2bf(a / (1.f + __expf(-a)));
            }
        }
    }
    __syncthreads();

    f32x4 acc2[2][4] = {};
    {
        const unsigned short* hrow = &smem[(wr * 32 + l15) * 136 + l4 * 8];
        const unsigned short* bb0  = wn2t + (wc * 64 + l15) * 128 + l4 * 8;
        #pragma unroll
        for (int ks = 0; ks < 4; ++ks) {
            bf16x8 a0 = *(const bf16x8*)(hrow + ks * 32);
            bf16x8 a1 = *(const bf16x8*)(hrow + 16 * 136 + ks * 32);
            #pragma unroll
            for (int n = 0; n < 4; ++n) {
                bf16x8 bb = *(const bf16x8*)(bb0 + n * 16 * 128 + ks * 32);
                acc2[0][n] = __builtin_amdgcn_mfma_f32_16x16x32_bf16(a0, bb, acc2[0][n], 0, 0, 0);
                acc2[1][n] = __builtin_amdgcn_mfma_f32_16x16x32_bf16(a1, bb, acc2[1][n], 0, 0, 0);
            }
        }
    }

    #pragma unroll
    for (int n = 0; n < 4; ++n) {
        int col = wc * 64 + n * 16 + l15;
        float bias = bn2[col];
        #pragma unroll
        for (int m = 0; m < 2; ++m) {
            #pragma unroll
            for (int i = 0; i < 4; ++i) {
                long long row = nflat0 + wr * 32 + m * 16 + l4 * 4 + i;
                node_emb[row * 128 + col] = acc2[m][n][i] + bias;
            }
        }
    }
}

// ------------------------------------------------------------ attention kernel
__global__ __launch_bounds__(256)
void attn_kernel(const float* __restrict__ blocks, const float* __restrict__ node_emb,
                 const float* __restrict__ w_attn, const float* __restrict__ rms_w,
                 float* __restrict__ out)
{
    const int t    = threadIdx.x;
    const int wave = t >> 6;
    const int lane = t & 63;
    const long long node = (long long)blockIdx.x * 4 + wave;
    const int d0 = lane * 2;

    float2 wa = *(const float2*)(w_attn + d0);
    float2 rw = *(const float2*)(rms_w + d0);

    float xs[5][2];
    float lg[5];
    #pragma unroll
    for (int s = 0; s < 5; ++s) {
        const float* src = (s < 4)
            ? (blocks + ((long long)s * NBATCH * NNODES + node) * 128)
            : (node_emb + node * 128);
        float2 x = *(const float2*)(src + d0);
        xs[s][0] = x.x; xs[s][1] = x.y;
        float ss = x.x * x.x + x.y * x.y;
        float wv = wa.x * rw.x * x.x + wa.y * rw.y * x.y;
        #pragma unroll
        for (int m = 1; m < 64; m <<= 1) {
            ss += __shfl_xor(ss, m);
            wv += __shfl_xor(wv, m);
        }
        lg[s] = wv * rsqrtf(ss * (1.f / 128.f) + 1e-6f);
    }

    float mx = lg[0];
    #pragma unroll
    for (int s = 1; s < 5; ++s) mx = fmaxf(mx, lg[s]);
    float ex[5], sum = 0.f;
    #pragma unroll
    for (int s = 0; s < 5; ++s) { ex[s] = __expf(lg[s] - mx); sum += ex[s]; }
    float inv = 1.f / sum;

    float h0 = 0.f, h1 = 0.f;
    #pragma unroll
    for (int s = 0; s < 5; ++s) {
        float a = ex[s] * inv;
        h0 = fmaf(a, xs[s][0], h0);
        h1 = fmaf(a, xs[s][1], h1);
    }
    *(float2*)(out + node * 128 + d0) = make_float2(h0, h1);
}

// ------------------------------------------------------------------- launcher
extern "C" void kernel_launch(void* const* d_in, const int* in_sizes, int n_in,
                              void* d_out, int out_size, void* d_ws, size_t ws_size,
                              hipStream_t stream)
{
    const float* V      = (const float*)d_in[0];
    const float* E      = (const float*)d_in[1];
    const float* blocks = (const float*)d_in[2];
    const float* We1    = (const float*)d_in[3];
    const float* be1    = (const float*)d_in[4];
    const float* We2    = (const float*)d_in[5];
    const float* be2    = (const float*)d_in[6];
    const float* Wn1    = (const float*)d_in[7];
    const float* bn1    = (const float*)d_in[8];
    const float* Wn2    = (const float*)d_in[9];
    const float* bn2    = (const float*)d_in[10];
    const float* w_attn = (const float*)d_in[11];
    const float* rms_w  = (const float*)d_in[12];
    const int*   edges  = (const int*)d_in[13];
    float* out = (float*)d_out;

    float* ws = (float*)d_ws;
    float* m0sum    = ws;                         // BS*N*64
    float* m1sum    = m0sum + 2097152;
    float* c0       = m1sum + 2097152;
    float* c1       = c0 + 32768;
    float* node_emb = c1 + 32768;                 // BS*N*128
    unsigned short* wbf = (unsigned short*)(node_emb + 4194304);  // 114688 bf16
    unsigned short* w1f  = wbf;            // 49152 (frag-ordered We1)
    unsigned short* w2f  = wbf + 49152;    // 16384 (frag-ordered We2)
    unsigned short* wn1t = wbf + 65536;    // 32768
    unsigned short* wn2t = wbf + 98304;    // 16384

    (void)hipMemsetAsync(d_ws, 0, (size_t)(2097152 * 2 + 32768 * 2) * sizeof(float), stream);

    prep_weights<<<448, 256, 0, stream>>>(We1, We2, Wn1, Wn2, wbf);

    edge_kernel<<<(NBATCH * NEDGES) / TE, 256, 0, stream>>>(
        V, E, edges, w1f, be1, w2f, be2, m0sum, m1sum, c0, c1);

    node_kernel<<<(NBATCH * NNODES) / TE, 256, 0, stream>>>(
        V, m0sum, m1sum, c0, c1, wn1t, bn1, wn2t, bn2, node_emb);

    attn_kernel<<<(NBATCH * NNODES) / 4, 256, 0, stream>>>(
        blocks, node_emb, w_attn, rms_w, out);
}

// Round 7
// 383.851 us; speedup vs baseline: 5.0587x; 1.4521x over previous
//
#include <hip/hip_runtime.h>
#include <hip/hip_bf16.h>

#define D 128
#define NNODES 16384
#define NEDGES 262144
#define NBATCH 2
#define TE 64

typedef __attribute__((ext_vector_type(8))) short bf16x8;
typedef __attribute__((ext_vector_type(4))) float f32x4;

__device__ __forceinline__ unsigned short f2bf(float f) {
    unsigned int u = __float_as_uint(f);
    unsigned int r = (u + 0x7fffu + ((u >> 16) & 1u)) >> 16;
    return (unsigned short)r;
}

__device__ __forceinline__ unsigned int pk2bf(float lo, float hi) {
    return (unsigned int)f2bf(lo) | ((unsigned int)f2bf(hi) << 16);
}

__device__ __forceinline__ float bf2f(unsigned short u) {
    return __uint_as_float(((unsigned int)u) << 16);
}

// --------------------------------------------------------------- weight prep
// wbf layout (ushort offsets):
//   w1ef @ 0     : We1 E-part (rows 256..383) in MFMA B-frag order, ks<4
//   w2f  @ 16384 : We2 frag order, ks<4
//   wp   @ 32768 : [W1s|W1r] as [j][k]: wp[j*128+k] = We1[(j<128?k:128+k)][j&127]
//   wn1t @ 65536 : Wn1^T [n][k] k<256
//   wn2t @ 98304 : Wn2^T [n][k] k<128
__global__ __launch_bounds__(256)
void prep_weights(const float* __restrict__ We1, const float* __restrict__ We2,
                  const float* __restrict__ Wn1, const float* __restrict__ Wn2,
                  unsigned short* __restrict__ w)
{
    int id = blockIdx.x * 256 + threadIdx.x;   // 114688 total
    if (id < 16384) {
        int e = id & 7, l = (id >> 3) & 63, nblk = (id >> 9) & 7, ks = id >> 12;
        int k = 256 + ks * 32 + ((l >> 4) & 3) * 8 + e;
        int col = nblk * 16 + (l & 15);
        w[id] = f2bf(We1[k * 128 + col]);
    } else if (id < 32768) {
        int i2 = id - 16384;
        int e = i2 & 7, l = (i2 >> 3) & 63, nblk = (i2 >> 9) & 7, ks = i2 >> 12;
        int k = ks * 32 + ((l >> 4) & 3) * 8 + e;
        int col = nblk * 16 + (l & 15);
        w[id] = f2bf(We2[k * 128 + col]);
    } else if (id < 65536) {
        int i3 = id - 32768;
        int j = i3 >> 7, k = i3 & 127;
        int row = (j < 128) ? k : (128 + k);
        w[id] = f2bf(We1[row * 128 + (j & 127)]);
    } else if (id < 98304) {
        int i4 = id - 65536;
        int n = i4 >> 8, k = i4 & 255;
        w[id] = f2bf(Wn1[k * 128 + n]);
    } else {
        int i5 = id - 98304;
        int n = i5 >> 7, k = i5 & 127;
        w[id] = f2bf(Wn2[k * 128 + n]);
    }
}

// ------------------------------------------------------------ partial kernel
// P[r][j] = sum_k V[r][k] * wp[j][k],  r < 32768 (flat b*N+n), j < 256.
// j<128 -> sender partial (W1s), j>=128 -> receiver partial (W1r). bf16 out.
__global__ __launch_bounds__(256)
void partial_kernel(const float* __restrict__ V, const unsigned short* __restrict__ wp,
                    unsigned short* __restrict__ P)
{
    __shared__ unsigned short smem[64 * 136];
    const int t = threadIdx.x, lane = t & 63, wave = t >> 6;
    const int l15 = lane & 15, l4 = lane >> 4;
    const long long r0 = (long long)blockIdx.x * 64;

    for (int i = t; i < 64 * 32; i += 256) {
        int c4 = i & 31, r = i >> 5;
        float4 v = *(const float4*)(V + (r0 + r) * 128 + c4 * 4);
        uint2 p; p.x = pk2bf(v.x, v.y); p.y = pk2bf(v.z, v.w);
        *(uint2*)(&smem[r * 136 + c4 * 4]) = p;
    }
    __syncthreads();

    const int j0 = wave * 64;
    f32x4 acc[4][4] = {};
    const unsigned short* bb0 = wp + (j0 + l15) * 128 + l4 * 8;
    #pragma unroll
    for (int ks = 0; ks < 4; ++ks) {
        bf16x8 bb[4];
        #pragma unroll
        for (int n = 0; n < 4; ++n)
            bb[n] = *(const bf16x8*)(bb0 + n * 16 * 128 + ks * 32);
        #pragma unroll
        for (int mq = 0; mq < 4; ++mq) {
            bf16x8 a = *(const bf16x8*)(&smem[(mq * 16 + l15) * 136 + l4 * 8 + ks * 32]);
            #pragma unroll
            for (int n = 0; n < 4; ++n)
                acc[mq][n] = __builtin_amdgcn_mfma_f32_16x16x32_bf16(a, bb[n], acc[mq][n], 0, 0, 0);
        }
    }
    #pragma unroll
    for (int mq = 0; mq < 4; ++mq) {
        #pragma unroll
        for (int n = 0; n < 4; ++n) {
            #pragma unroll
            for (int i = 0; i < 4; ++i) {
                int row = mq * 16 + l4 * 4 + i;
                int col = j0 + n * 16 + l15;
                P[(r0 + row) * 256 + col] = f2bf(acc[mq][n][i]);
            }
        }
    }
}

// ---------------------------------------------------------------- edge kernel
// 64 edges/block, 4 waves (2 row-blocks x 2 col-blocks). No V-gather:
// layer1 = E @ W1e (sequential staging, K=128) + scalar gather-add of
// precomputed P[snd], P[rcv] partials in the epilogue. LDS 17.9KB -> 8 blk/CU.
__global__ __launch_bounds__(256)
void edge_kernel(const float* __restrict__ E, const int* __restrict__ edges,
                 const unsigned short* __restrict__ P,
                 const unsigned short* __restrict__ w1ef, const float* __restrict__ be1,
                 const unsigned short* __restrict__ w2f, const float* __restrict__ be2,
                 float* __restrict__ m0sum, float* __restrict__ m1sum,
                 float* __restrict__ c0, float* __restrict__ c1)
{
    __shared__ unsigned short smem[TE * 136];   // E tile, reused as H tile
    __shared__ int eidx[TE][2];

    const int t    = threadIdx.x;
    const int lane = t & 63;
    const int wave = t >> 6;
    const int wr   = wave >> 1;
    const int wc   = wave & 1;
    const int l15  = lane & 15;
    const int l4   = lane >> 4;

    const long long eflat0 = (long long)blockIdx.x * TE;
    const int b  = (int)(eflat0 / NEDGES);

    if (t < TE * 2) {
        eidx[t >> 1][t & 1] = edges[(eflat0 + (t >> 1)) * 2 + (t & 1)];
    }
    // stage E rows (fully coalesced, sequential)
    for (int i = t; i < TE * 32; i += 256) {
        int c4 = i & 31, e = i >> 5;
        float4 v = *(const float4*)(E + (eflat0 + e) * D + c4 * 4);
        uint2 p; p.x = pk2bf(v.x, v.y); p.y = pk2bf(v.z, v.w);
        *(uint2*)(&smem[e * 136 + c4 * 4]) = p;
    }
    __syncthreads();

    // ---- layer 1 (E part only): [64x128] @ [128x128] ----
    f32x4 acc[2][4] = {};
    {
        const unsigned short* arow = &smem[(wr * 32 + l15) * 136 + l4 * 8];
        #pragma unroll
        for (int ks = 0; ks < 4; ++ks) {
            bf16x8 a0 = *(const bf16x8*)(arow + ks * 32);
            bf16x8 a1 = *(const bf16x8*)(arow + 16 * 136 + ks * 32);
            #pragma unroll
            for (int n = 0; n < 4; ++n) {
                bf16x8 bb = *(const bf16x8*)(w1ef + (((ks * 8 + wc * 4 + n) * 64 + lane) << 3));
                acc[0][n] = __builtin_amdgcn_mfma_f32_16x16x32_bf16(a0, bb, acc[0][n], 0, 0, 0);
                acc[1][n] = __builtin_amdgcn_mfma_f32_16x16x32_bf16(a1, bb, acc[1][n], 0, 0, 0);
            }
        }
    }
    __syncthreads();   // all waves done reading E tile

    // epilogue: + P[snd] (sender partial) + P[rcv] (receiver partial) + bias, silu
    const long long pb0 = (long long)b * NNODES;
    #pragma unroll
    for (int n = 0; n < 4; ++n) {
        int col = wc * 64 + n * 16 + l15;
        float bias = be1[col];
        #pragma unroll
        for (int m = 0; m < 2; ++m) {
            #pragma unroll
            for (int i = 0; i < 4; ++i) {
                int row = wr * 32 + m * 16 + l4 * 4 + i;
                long long ps = (pb0 + eidx[row][0]) * 256 + col;
                long long pr = (pb0 + eidx[row][1]) * 256 + 128 + col;
                float a = acc[m][n][i] + bias + bf2f(P[ps]) + bf2f(P[pr]);
                smem[row * 136 + col] = f2bf(a / (1.f + __expf(-a)));
            }
        }
    }
    __syncthreads();

    // ---- layer 2: [64x128] @ [128x128] ----
    f32x4 acc2[2][4] = {};
    {
        const unsigned short* hrow = &smem[(wr * 32 + l15) * 136 + l4 * 8];
        #pragma unroll
        for (int ks = 0; ks < 4; ++ks) {
            bf16x8 a0 = *(const bf16x8*)(hrow + ks * 32);
            bf16x8 a1 = *(const bf16x8*)(hrow + 16 * 136 + ks * 32);
            #pragma unroll
            for (int n = 0; n < 4; ++n) {
                bf16x8 bb = *(const bf16x8*)(w2f + (((ks * 8 + wc * 4 + n) * 64 + lane) << 3));
                acc2[0][n] = __builtin_amdgcn_mfma_f32_16x16x32_bf16(a0, bb, acc2[0][n], 0, 0, 0);
                acc2[1][n] = __builtin_amdgcn_mfma_f32_16x16x32_bf16(a1, bb, acc2[1][n], 0, 0, 0);
            }
        }
    }

    // scatter: 16 consecutive lanes = 16 consecutive feats of one node
    float* dst_arr = wc ? m1sum : m0sum;
    const long long nb0 = (long long)b * NNODES;
    #pragma unroll
    for (int n = 0; n < 4; ++n) {
        int colh = n * 16 + l15;
        float bias = be2[wc * 64 + colh];
        #pragma unroll
        for (int m = 0; m < 2; ++m) {
            #pragma unroll
            for (int i = 0; i < 4; ++i) {
                int erow = wr * 32 + m * 16 + l4 * 4 + i;
                int node = eidx[erow][wc];
                atomicAdd(dst_arr + (nb0 + node) * 64 + colh,
                          acc2[m][n][i] + bias);
            }
        }
    }
    if (t < TE)          atomicAdd(&c0[nb0 + eidx[t][0]], 1.f);
    else if (t < 2 * TE) atomicAdd(&c1[nb0 + eidx[t - TE][1]], 1.f);
}

// ---------------------------------------------------------------- node kernel
__global__ __launch_bounds__(256)
void node_kernel(const float* __restrict__ V,
                 const float* __restrict__ m0sum, const float* __restrict__ m1sum,
                 const float* __restrict__ c0, const float* __restrict__ c1,
                 const unsigned short* __restrict__ wn1t, const float* __restrict__ bn1,
                 const unsigned short* __restrict__ wn2t, const float* __restrict__ bn2,
                 float* __restrict__ node_emb)
{
    __shared__ unsigned short smem[TE * 264];   // A [64][264]; reused as H [64][136]

    const int t    = threadIdx.x;
    const int lane = t & 63;
    const int wave = t >> 6;
    const int wr   = wave >> 1;
    const int wc   = wave & 1;
    const int l15  = lane & 15;
    const int l4   = lane >> 4;

    const long long nflat0 = (long long)blockIdx.x * TE;

    for (int i = t; i < TE * 64; i += 256) {
        int c4 = i & 63;
        int n  = i >> 6;
        long long node = nflat0 + n;
        float4 v; int off;
        if (c4 < 32) {
            v = *(const float4*)(V + node * 128 + c4 * 4);
            off = c4 * 4;
        } else if (c4 < 48) {
            v = *(const float4*)(m0sum + node * 64 + (c4 - 32) * 4);
            float inv = 1.f / fmaxf(c0[node], 1.f);
            v.x *= inv; v.y *= inv; v.z *= inv; v.w *= inv;
            off = 128 + (c4 - 32) * 4;
        } else {
            v = *(const float4*)(m1sum + node * 64 + (c4 - 48) * 4);
            float inv = 1.f / fmaxf(c1[node], 1.f);
            v.x *= inv; v.y *= inv; v.z *= inv; v.w *= inv;
            off = 192 + (c4 - 48) * 4;
        }
        uint2 p;
        p.x = pk2bf(v.x, v.y);
        p.y = pk2bf(v.z, v.w);
        *(uint2*)(&smem[n * 264 + c4 * 4]) = p;
    }
    __syncthreads();

    f32x4 acc[2][4] = {};
    {
        const unsigned short* arow = &smem[(wr * 32 + l15) * 264 + l4 * 8];
        const unsigned short* bb0  = wn1t + (wc * 64 + l15) * 256 + l4 * 8;
        for (int ks = 0; ks < 8; ++ks) {
            bf16x8 a0 = *(const bf16x8*)(arow + ks * 32);
            bf16x8 a1 = *(const bf16x8*)(arow + 16 * 264 + ks * 32);
            #pragma unroll
            for (int n = 0; n < 4; ++n) {
                bf16x8 bb = *(const bf16x8*)(bb0 + n * 16 * 256 + ks * 32);
                acc[0][n] = __builtin_amdgcn_mfma_f32_16x16x32_bf16(a0, bb, acc[0][n], 0, 0, 0);
                acc[1][n] = __builtin_amdgcn_mfma_f32_16x16x32_bf16(a1, bb, acc[1][n], 0, 0, 0);
            }
        }
    }
    __syncthreads();

    #pragma unroll
    for (int n = 0; n < 4; ++n) {
        int col = wc * 64 + n * 16 + l15;
        float bias = bn1[col];
        #pragma unroll
        for (int m = 0; m < 2; ++m) {
            #pragma unroll
            for (int i = 0; i < 4; ++i) {
                int row = wr * 32 + m * 16 + l4 * 4 + i;
                float a = acc[m][n][i] + bias;
                smem[row * 136 + col] = f2bf(a / (1.f + __expf(-a)));
            }
        }
    }
    __syncthreads();

    f32x4 acc2[2][4] = {};
    {
        const unsigned short* hrow = &smem[(wr * 32 + l15) * 136 + l4 * 8];
        const unsigned short* bb0  = wn2t + (wc * 64 + l15) * 128 + l4 * 8;
        #pragma unroll
        for (int ks = 0; ks < 4; ++ks) {
            bf16x8 a0 = *(const bf16x8*)(hrow + ks * 32);
            bf16x8 a1 = *(const bf16x8*)(hrow + 16 * 136 + ks * 32);
            #pragma unroll
            for (int n = 0; n < 4; ++n) {
                bf16x8 bb = *(const bf16x8*)(bb0 + n * 16 * 128 + ks * 32);
                acc2[0][n] = __builtin_amdgcn_mfma_f32_16x16x32_bf16(a0, bb, acc2[0][n], 0, 0, 0);
                acc2[1][n] = __builtin_amdgcn_mfma_f32_16x16x32_bf16(a1, bb, acc2[1][n], 0, 0, 0);
            }
        }
    }

    #pragma unroll
    for (int n = 0; n < 4; ++n) {
        int col = wc * 64 + n * 16 + l15;
        float bias = bn2[col];
        #pragma unroll
        for (int m = 0; m < 2; ++m) {
            #pragma unroll
            for (int i = 0; i < 4; ++i) {
                long long row = nflat0 + wr * 32 + m * 16 + l4 * 4 + i;
                node_emb[row * 128 + col] = acc2[m][n][i] + bias;
            }
        }
    }
}

// ------------------------------------------------------------ attention kernel
__global__ __launch_bounds__(256)
void attn_kernel(const float* __restrict__ blocks, const float* __restrict__ node_emb,
                 const float* __restrict__ w_attn, const float* __restrict__ rms_w,
                 float* __restrict__ out)
{
    const int t    = threadIdx.x;
    const int wave = t >> 6;
    const int lane = t & 63;
    const long long node = (long long)blockIdx.x * 4 + wave;
    const int d0 = lane * 2;

    float2 wa = *(const float2*)(w_attn + d0);
    float2 rw = *(const float2*)(rms_w + d0);

    float xs[5][2];
    float lg[5];
    #pragma unroll
    for (int s = 0; s < 5; ++s) {
        const float* src = (s < 4)
            ? (blocks + ((long long)s * NBATCH * NNODES + node) * 128)
            : (node_emb + node * 128);
        float2 x = *(const float2*)(src + d0);
        xs[s][0] = x.x; xs[s][1] = x.y;
        float ss = x.x * x.x + x.y * x.y;
        float wv = wa.x * rw.x * x.x + wa.y * rw.y * x.y;
        #pragma unroll
        for (int m = 1; m < 64; m <<= 1) {
            ss += __shfl_xor(ss, m);
            wv += __shfl_xor(wv, m);
        }
        lg[s] = wv * rsqrtf(ss * (1.f / 128.f) + 1e-6f);
    }

    float mx = lg[0];
    #pragma unroll
    for (int s = 1; s < 5; ++s) mx = fmaxf(mx, lg[s]);
    float ex[5], sum = 0.f;
    #pragma unroll
    for (int s = 0; s < 5; ++s) { ex[s] = __expf(lg[s] - mx); sum += ex[s]; }
    float inv = 1.f / sum;

    float h0 = 0.f, h1 = 0.f;
    #pragma unroll
    for (int s = 0; s < 5; ++s) {
        float a = ex[s] * inv;
        h0 = fmaf(a, xs[s][0], h0);
        h1 = fmaf(a, xs[s][1], h1);
    }
    *(float2*)(out + node * 128 + d0) = make_float2(h0, h1);
}

// ------------------------------------------------------------------- launcher
extern "C" void kernel_launch(void* const* d_in, const int* in_sizes, int n_in,
                              void* d_out, int out_size, void* d_ws, size_t ws_size,
                              hipStream_t stream)
{
    const float* V      = (const float*)d_in[0];
    const float* E      = (const float*)d_in[1];
    const float* blocks = (const float*)d_in[2];
    const float* We1    = (const float*)d_in[3];
    const float* be1    = (const float*)d_in[4];
    const float* We2    = (const float*)d_in[5];
    const float* be2    = (const float*)d_in[6];
    const float* Wn1    = (const float*)d_in[7];
    const float* bn1    = (const float*)d_in[8];
    const float* Wn2    = (const float*)d_in[9];
    const float* bn2    = (const float*)d_in[10];
    const float* w_attn = (const float*)d_in[11];
    const float* rms_w  = (const float*)d_in[12];
    const int*   edges  = (const int*)d_in[13];
    float* out = (float*)d_out;

    float* ws = (float*)d_ws;
    float* m0sum    = ws;                         // BS*N*64
    float* m1sum    = m0sum + 2097152;
    float* c0       = m1sum + 2097152;
    float* c1       = c0 + 32768;
    float* node_emb = c1 + 32768;                 // BS*N*128
    unsigned short* wbf = (unsigned short*)(node_emb + 4194304);  // 114688 bf16
    unsigned short* w1ef = wbf;            // 16384 (frag-ordered We1 E-part)
    unsigned short* w2f  = wbf + 16384;    // 16384 (frag-ordered We2)
    unsigned short* wp   = wbf + 32768;    // 32768 ([W1s|W1r] transposed)
    unsigned short* wn1t = wbf + 65536;    // 32768
    unsigned short* wn2t = wbf + 98304;    // 16384
    unsigned short* P    = wbf + 114688;   // 32768*256 bf16 partials (16.8MB)

    (void)hipMemsetAsync(d_ws, 0, (size_t)(2097152 * 2 + 32768 * 2) * sizeof(float), stream);

    prep_weights<<<448, 256, 0, stream>>>(We1, We2, Wn1, Wn2, wbf);

    partial_kernel<<<(NBATCH * NNODES) / 64, 256, 0, stream>>>(V, wp, P);

    edge_kernel<<<(NBATCH * NEDGES) / TE, 256, 0, stream>>>(
        E, edges, P, w1ef, be1, w2f, be2, m0sum, m1sum, c0, c1);

    node_kernel<<<(NBATCH * NNODES) / TE, 256, 0, stream>>>(
        V, m0sum, m1sum, c0, c1, wn1t, bn1, wn2t, bn2, node_emb);

    attn_kernel<<<(NBATCH * NNODES) / 4, 256, 0, stream>>>(
        blocks, node_emb, w_attn, rms_w, out);
}